// Round 6
// baseline (78.456 us; speedup 1.0000x reference)
//
#include <hip/hip_runtime.h>

#define BB 8
#define NC 12
#define NC1 11
#define HH 512
#define WW 512
#define NCH 32     // 16-h chunks per column
#define HC 16
#define NBC (BB*NC1) // 88

static constexpr size_t CH = (size_t)HH * WW;   // 262144

// output offsets (flat floats, in return order)
static constexpr size_t OFF_LSM   = 0;
static constexpr size_t OFF_CLP   = (size_t)BB * NC1 * CH;                 // 23068672
static constexpr size_t OFF_CLEAN = OFF_CLP + (size_t)BB * NC1 * WW;       // 23113728
static constexpr size_t OFF_STD   = OFF_CLEAN + (size_t)BB * NC * CH;      // 48279552
static constexpr size_t OFF_TOPO  = OFF_STD + (size_t)BB * NC1 * WW;
static constexpr size_t OFF_CONT  = OFF_TOPO + (size_t)BB * (NC1 - 1) * WW;
static constexpr size_t OFF_CURV  = OFF_CONT + (size_t)BB * NC1 * (WW - 1);

// workspace layout (floats)
static constexpr size_t WS_E    = 0;                              // [88][32][512] -> later chunk cum-bases
static constexpr size_t WS_P    = (size_t)NBC * NCH * WW;         // 1441792
static constexpr size_t WS_Q    = 2 * WS_P;
static constexpr size_t WS_INV  = 3 * WS_P;                       // [88][512]
static constexpr size_t WS_LOG  = WS_INV + (size_t)NBC * WW;
static constexpr size_t WS_LP   = WS_LOG + (size_t)NBC * WW;

// ---------------------------------------------------------------- K1: chunk partials (float4 streaming)
// grid (8 chunk-groups, 88 bc) = 704 blocks x 512 thr; no barriers
__global__ __launch_bounds__(512) void k1_partials(const float* __restrict__ in,
                                                   float* __restrict__ ws) {
    const int w4 = threadIdx.x & 127;     // float4 lane: w = 4*w4
    const int cg = threadIdx.x >> 7;      // 0..3
    const int chunk = blockIdx.x * 4 + cg;
    const int bc = blockIdx.y;
    const int b = bc / NC1, c = bc % NC1;

    const float* p = in + ((size_t)(b * NC + c) * HH + (size_t)chunk * HC) * WW + 4 * w4;
    float4 E = make_float4(0.f, 0.f, 0.f, 0.f);
    float4 P = E, Q = E;
#pragma unroll
    for (int i = 0; i < HC; ++i) {
        const float4 x = *(const float4*)(p + (size_t)i * WW);
        const float h = (float)(chunk * HC + i);
        const float ex = expf(x.x), ey = expf(x.y), ez = expf(x.z), ew = expf(x.w);
        E.x += ex; E.y += ey; E.z += ez; E.w += ew;
        P.x += h * ex; P.y += h * ey; P.z += h * ez; P.w += h * ew;
        Q.x += h * h * ex; Q.y += h * h * ey; Q.z += h * h * ez; Q.w += h * h * ew;
    }
    const size_t o = ((size_t)bc * NCH + chunk) * WW + 4 * w4;
    *(float4*)(ws + WS_E + o) = E;
    *(float4*)(ws + WS_P + o) = P;
    *(float4*)(ws + WS_Q + o) = Q;
}

// ---------------------------------------------------------------- K2: parallel per-column reduce
// grid (4 wtiles, 88 bc) = 352 blocks x 512 thr (w=tid&127, q=tid>>7 owns 8 chunks)
__global__ __launch_bounds__(512) void k2_reduce(float* __restrict__ ws,
                                                 float* __restrict__ out) {
    const int w = threadIdx.x & 127;
    const int q = threadIdx.x >> 7;       // wave-uniform quarter 0..3
    const int wt = blockIdx.x;            // 0..3
    const int bc = blockIdx.y;            // 0..87
    const int wg = wt * 128 + w;

    __shared__ float sE[4][128], sP[4][128], sQ[4][128];

    const size_t base = (size_t)bc * NCH * WW + wg;
    float e[8];
    float Es = 0.f, Ps = 0.f, Qs = 0.f;
#pragma unroll
    for (int k = 0; k < 8; ++k) {
        const int ch = q * 8 + k;
        e[k] = ws[WS_E + base + (size_t)ch * WW];
        Es += e[k];
        Ps += ws[WS_P + base + (size_t)ch * WW];
        Qs += ws[WS_Q + base + (size_t)ch * WW];
    }
    sE[q][w] = Es; sP[q][w] = Ps; sQ[q][w] = Qs;
    __syncthreads();

    const float S = sE[0][w] + sE[1][w] + sE[2][w] + sE[3][w];
    const float inv = 1.f / S;
    float pre = 0.f;
    for (int q2 = 0; q2 < q; ++q2) pre += sE[q2][w];  // q wave-uniform: no divergence
#pragma unroll
    for (int k = 0; k < 8; ++k) {   // normalized cumsum base BEFORE each chunk (in place over E)
        const int ch = q * 8 + k;
        ws[WS_E + base + (size_t)ch * WW] = pre * inv;
        pre += e[k];
    }
    if (q == 0) {
        const float P = sP[0][w] + sP[1][w] + sP[2][w] + sP[3][w];
        const float Q = sQ[0][w] + sQ[1][w] + sQ[2][w] + sQ[3][w];
        const float lp = P * inv;
        float var = Q * inv - lp * lp;
        if (var < 0.f) var = 0.f;
        const size_t o = (size_t)bc * WW + wg;
        ws[WS_INV + o] = inv;
        ws[WS_LOG + o] = logf(S);
        ws[WS_LP + o]  = lp;
        out[OFF_STD + o] = sqrtf(var);
    }
}

// ---------------------------------------------------------------- K4: lsm + clean_masks + smalls (plain stores)
// grid (2 whalf, 32 chunk, 8 b) = 512 blocks x 256 thr
__global__ __launch_bounds__(256) void k4_main(const float* __restrict__ in,
                                               const float* __restrict__ ws,
                                               float* __restrict__ out) {
    const int t = threadIdx.x;
    const int wh = blockIdx.x, chunk = blockIdx.y, b = blockIdx.z;
    const int w = wh * 256 + t;

    float cum[NC1], inv[NC1], lgs[NC1];
#pragma unroll
    for (int c = 0; c < NC1; ++c) {
        const size_t bc = (size_t)(b * NC1 + c);
        cum[c] = ws[WS_E + (bc * NCH + chunk) * WW + w];
        inv[c] = ws[WS_INV + bc * WW + w];
        lgs[c] = ws[WS_LOG + bc * WW + w];
    }

    const float* ip = in + (size_t)b * NC * CH + (size_t)(chunk * HC) * WW + w;
    float* lsm = out + OFF_LSM + (size_t)b * NC1 * CH + (size_t)(chunk * HC) * WW + w;
    float* cln = out + OFF_CLEAN + (size_t)b * NC * CH + (size_t)(chunk * HC) * WW + w;

    for (int i = 0; i < HC; ++i) {
        const size_t ho = (size_t)i * WW;
        float x[NC1];
#pragma unroll
        for (int c = 0; c < NC1; ++c)
            x[c] = ip[(size_t)c * CH + ho];
#pragma unroll
        for (int c = 0; c < NC1; ++c) {
            cum[c] += expf(x[c]) * inv[c];
            lsm[(size_t)c * CH + ho] = x[c] - lgs[c];
        }
        float tc = cum[0];
        cln[ho] = 1.f - tc;
#pragma unroll
        for (int k = 1; k < NC1; ++k) {
            const float t2 = fmaxf(cum[k] + tc - 1.f, 0.f);
            cln[(size_t)k * CH + ho] = tc - t2;
            tc = t2;
        }
        cln[(size_t)NC1 * CH + ho] = tc;
    }

    if (chunk != 0) return;
    // ---- smalls: cummax / topology / continuity / curvature from lp
    const float CM[NC1] = {1.2261f, 1.1558f, 1.1161f, 1.1195f, 2.7202f, 2.3714f,
                           1.7055f, 3.2717f, 2.6716f, 5.0418f, 0.4293f};
    const float* lp = ws + WS_LP;
    const int wm = (w - 5 < 0) ? 0 : w - 5;
    const int wp = (w + 5 > WW - 1) ? WW - 1 : w + 5;
    float m = 0.f, prev = 0.f;
    for (int c = 0; c < NC1; ++c) {
        const size_t rb = (size_t)(b * NC1 + c) * WW;
        const float lv = lp[rb + w];
        m = (c == 0) ? lv : fmaxf(m, lv);
        out[OFF_CLP + rb + w] = m;
        if (c > 0)
            out[OFF_TOPO + (size_t)(b * (NC1 - 1) + (c - 1)) * WW + w] = fmaxf(prev - lv, 0.f);
        prev = lv;
        if (w < WW - 1) {
            const float nxt = lp[rb + w + 1];
            out[OFF_CONT + (size_t)(b * NC1 + c) * (WW - 1) + w] = fabsf(lv - nxt);
        }
        const float a  = lp[rb + wm];
        const float bb = lp[rb + wp];
        const float fo = bb - a;
        const float so = a - 2.f * lv + bb;
        const float bs = 1.f + fo * fo;
        out[OFF_CURV + rb + w] = fabsf(so / (bs * sqrtf(bs))) - CM[c];
    }
}

extern "C" void kernel_launch(void* const* d_in, const int* in_sizes, int n_in,
                              void* d_out, int out_size, void* d_ws, size_t ws_size,
                              hipStream_t stream) {
    const float* in = (const float*)d_in[0];
    float* out = (float*)d_out;
    float* ws = (float*)d_ws;

    hipLaunchKernelGGL(k1_partials, dim3(NCH / 4, NBC), dim3(512), 0, stream, in, ws);
    hipLaunchKernelGGL(k2_reduce, dim3(4, NBC), dim3(512), 0, stream, ws, out);
    hipLaunchKernelGGL(k4_main, dim3(2, NCH, BB), dim3(256), 0, stream, in, ws, out);
}